// Round 15
// baseline (106.536 us; speedup 1.0000x reference)
//
#include <hip/hip_runtime.h>

#define DEVI __device__ __forceinline__

typedef int i32x4 __attribute__((ext_vector_type(4)));

static constexpr int Bdim = 2048;
static constexpr int Kdim = 4096;
static constexpr int Ndim = 8192;
static constexpr int BK   = 64;          // int8 k per tile (64 B rows)
static constexpr int NT   = Kdim / BK;   // 64 tiles

typedef __attribute__((address_space(1))) const unsigned int gas_t;
typedef __attribute__((address_space(3))) unsigned int las_t;

DEVI void gload_lds16(const void* g, void* l) {
    __builtin_amdgcn_global_load_lds((gas_t*)g, (las_t*)l, 16, 0, 0);
}

DEVI int pack4(i32x4 v) {
    return (v[0] & 255) | ((v[1] & 255) << 8) | ((v[2] & 255) << 16) | (v[3] << 24);
}

// ---------------- pack: int32 -> int8 ----------------
__global__ void pack_i32_to_i8(const int* __restrict__ in, char* __restrict__ out, int n16) {
    int i = blockIdx.x * blockDim.x + threadIdx.x;
    if (i >= n16) return;
    const i32x4* src = (const i32x4*)in + (size_t)i * 4;
    i32x4 r;
    r[0] = pack4(src[0]);
    r[1] = pack4(src[1]);
    r[2] = pack4(src[2]);
    r[3] = pack4(src[3]);
    ((i32x4*)out)[i] = r;
}

// ------ 256x256 i8 GEMM, BK=64, 3 LDS bufs, 1 barrier/tile, wave stagger ------
// SIMD = wid%4 => waves wr=0 and wr=1 share a SIMD. wr=0 computes half0 then
// half1; wr=1 the reverse (sched_barrier pins the order). While one wave
// issues its 16-MFMA cluster, its SIMD partner issues ds_reads -> matrix pipe
// stays fed across the window (the role-split all prior symmetric builds lacked).
#define CFENCE asm volatile("" ::: "memory")
DEVI void bar() { CFENCE; __builtin_amdgcn_s_barrier(); CFENCE; }
#define WAITVM(N) asm volatile("s_waitcnt vmcnt(" #N ")" ::: "memory")
#define SCHB __builtin_amdgcn_sched_barrier(0)
#define PRIO1 __builtin_amdgcn_s_setprio(1)
#define PRIO0 __builtin_amdgcn_s_setprio(0)

// quad-half: acc[MB..MB+3][0..3] += a[MB..MB+3] x b[0..3]
#define QUADH(MB)                                                                \
    do {                                                                         \
        _Pragma("unroll") for (int mm = 0; mm < 4; ++mm)                         \
        _Pragma("unroll") for (int n = 0; n < 4; ++n)                            \
            acc[(MB) + mm][n] = __builtin_amdgcn_mfma_i32_16x16x64_i8(           \
                a[(MB) + mm], b[n], acc[(MB) + mm][n], 0, 0, 0);                 \
    } while (0)

#define LDAH(MB)                                                                 \
    _Pragma("unroll") for (int mm = 0; mm < 4; ++mm)                             \
        a[(MB) + mm] = smem4[cb + a_rd16 + ((MB) + mm) * 64]

__attribute__((amdgpu_waves_per_eu(2, 2)))
__global__ __launch_bounds__(512, 2)
void gemm14(const char* __restrict__ A8, const char* __restrict__ B8,
            const int* __restrict__ bias,
            const int* __restrict__ qm_p, const int* __restrict__ ex_p,
            const int* __restrict__ zp_p, int* __restrict__ out) {
    // LDS (16B units): [3 buf][ A 256x4slots | B 256x4slots ] = 96 KiB
    __shared__ i32x4 smem4[6144];
    char* smem = (char*)smem4;

    const int tid  = threadIdx.x;
    const int wid  = tid >> 6;
    const int lane = tid & 63;
    const int l15  = lane & 15;
    const int lks  = lane >> 4;
    const int wr   = wid >> 2;   // 0..1  == SIMD-partner parity
    const int wc   = wid & 3;    // 0..3

    // XCD-bijective swizzle (256 % 8 == 0)
    const int bid = blockIdx.x;
    const int swz = (bid & 7) * 32 + (bid >> 3);
    const int bm  = swz >> 5;    // 0..7
    const int bn  = swz & 31;    // 0..31
    const int arow0 = bm * 256;
    const int brow0 = bn * 256;

    // T2 swizzle (r10-verified 0-conflict): phys slot = chunk ^ ((row>>1)&3)
    const int swsel = lks ^ ((l15 >> 1) & 3);
    const int a_rd16 = (wr * 128 + l15) * 4 + swsel;
    const int b_rd16 = 1024 + (wc * 64 + l15) * 4 + swsel;

    // staging: thread covers rows tid>>2 (+128), chunk st_c (inverse swizzle)
    const int st_c = (tid & 3) ^ ((tid >> 3) & 3);
    const char* agp = A8 + (size_t)(arow0 + (tid >> 2)) * Kdim + st_c * 16;
    const char* bgp = B8 + (size_t)(brow0 + (tid >> 2)) * Kdim + st_c * 16;

    auto stage = [&](int t) {    // 4 gload_lds16 = full 32 KB tile
        const int lb = (t % 3) * 32768 + tid * 16;
        const size_t ko = (size_t)t * BK;
        gload_lds16(agp + ko,                      &smem[lb]);
        gload_lds16(agp + ko + (size_t)128 * Kdim, &smem[lb + 8192]);
        gload_lds16(bgp + ko,                      &smem[lb + 16384]);
        gload_lds16(bgp + ko + (size_t)128 * Kdim, &smem[lb + 24576]);
    };

    i32x4 acc[8][4] = {};

    // prologue: tiles 0,1 staged; tile 0 proven
    stage(0);
    stage(1);
    WAITVM(4);
    bar();

    for (int t = 0; t < NT; ++t) {
        const int cb = (t % 3) * 2048;       // 16B units
        if (t + 2 < NT) stage(t + 2);        // buf (t+2)%3: readers drained @bar(t-1)
        i32x4 a[8], b[4];
#pragma unroll
        for (int n = 0; n < 4; ++n) b[n] = smem4[cb + b_rd16 + n * 64];
        if (wr == 0) {
            LDAH(0);
            PRIO1; QUADH(0); PRIO0;
            SCHB;                            // pin: half1 reads stay below half0 MFMAs
            LDAH(4);
            PRIO1; QUADH(4); PRIO0;
        } else {
            LDAH(4);
            PRIO1; QUADH(4); PRIO0;
            SCHB;
            LDAH(0);
            PRIO1; QUADH(0); PRIO0;
        }
        if (t + 2 < NT) { WAITVM(4); }       // proves tile t+1 (4 oldest DMAs)
        else            { WAITVM(0); }
        bar();
    }

    // ---------------- epilogue: requantize ----------------
    const int qm = *qm_p;
    const int ex = *ex_p;
    const int zp = *zp_p;
    const int rm = (qm < 2147418112) ? ((qm + (1 << 15)) >> 16) : 32767;
    const int shifts = 15 - ex;
    const long long rnd = (shifts > 0) ? (1LL << (shifts - 1)) : 0;

    int bv[4];
#pragma unroll
    for (int n = 0; n < 4; ++n) bv[n] = bias[brow0 + wc * 64 + n * 16 + l15];

#pragma unroll
    for (int m = 0; m < 8; ++m) {
        const int row0 = arow0 + wr * 128 + m * 16 + lks * 4;
#pragma unroll
        for (int n = 0; n < 4; ++n) {
            const int col = brow0 + wc * 64 + n * 16 + l15;
#pragma unroll
            for (int j = 0; j < 4; ++j) {
                long long v = (long long)(acc[m][n][j] + bv[n]) * rm + rnd;
                v >>= shifts;
                v += zp;
                v = v < -128 ? -128 : (v > 127 ? 127 : v);
                out[(size_t)(row0 + j) * Ndim + col] = (int)v;
            }
        }
    }
}

extern "C" void kernel_launch(void* const* d_in, const int* in_sizes, int n_in,
                              void* d_out, int out_size, void* d_ws, size_t ws_size,
                              hipStream_t stream) {
    const int* x32  = (const int*)d_in[0];
    const int* w32  = (const int*)d_in[1];
    const int* bias = (const int*)d_in[2];
    const int* qm   = (const int*)d_in[3];
    const int* ex   = (const int*)d_in[4];
    const int* zp   = (const int*)d_in[5];
    int* out = (int*)d_out;

    char* xa = (char*)d_ws;
    char* wa = xa + (size_t)Bdim * Kdim;
    const int nx16 = Bdim * Kdim / 16;   // 524288
    const int nw16 = Ndim * Kdim / 16;   // 2097152
    pack_i32_to_i8<<<(nx16 + 255) / 256, 256, 0, stream>>>(x32, xa, nx16);
    pack_i32_to_i8<<<(nw16 + 255) / 256, 256, 0, stream>>>(w32, wa, nw16);

    const int grid = (Bdim / 256) * (Ndim / 256);   // 8 * 32 = 256
    gemm14<<<grid, 512, 0, stream>>>(xa, wa, bias, qm, ex, zp, out);
}

// Round 16
// 104.607 us; speedup vs baseline: 1.0184x; 1.0184x over previous
//
#include <hip/hip_runtime.h>

#define DEVI __device__ __forceinline__

typedef int i32x4 __attribute__((ext_vector_type(4)));

static constexpr int Bdim = 2048;
static constexpr int Kdim = 4096;
static constexpr int Ndim = 8192;
static constexpr int BK   = 64;          // int8 k per tile (64 B rows)
static constexpr int NT   = Kdim / BK;   // 64 tiles (even)

typedef __attribute__((address_space(1))) const unsigned int gas_t;
typedef __attribute__((address_space(3))) unsigned int las_t;

DEVI void gload_lds16(const void* g, void* l) {
    __builtin_amdgcn_global_load_lds((gas_t*)g, (las_t*)l, 16, 0, 0);
}

DEVI int pack4(i32x4 v) {
    return (v[0] & 255) | ((v[1] & 255) << 8) | ((v[2] & 255) << 16) | (v[3] << 24);
}

// ---------------- pack: int32 -> int8 ----------------
__global__ void pack_i32_to_i8(const int* __restrict__ in, char* __restrict__ out, int n16) {
    int i = blockIdx.x * blockDim.x + threadIdx.x;
    if (i >= n16) return;
    const i32x4* src = (const i32x4*)in + (size_t)i * 4;
    i32x4 r;
    r[0] = pack4(src[0]);
    r[1] = pack4(src[1]);
    r[2] = pack4(src[2]);
    r[3] = pack4(src[3]);
    ((i32x4*)out)[i] = r;
}

// ---- 256x256 i8 GEMM: reads 1 tile ahead, stage 3 ahead, 4 bufs, 1 bar/tile ----
// Reads for tile t+1 issue during tile t; their lgkm wait is COMPILER-inserted
// before MFMA(t+1) (counted: the 12 newer reads stay outstanding) -> LDS queue
// drains under MFMA(t). Ring proof: end of tile T proves stage(T+2) via
// WAITVM(4) (outstanding = stage(T+2),stage(T+3)); reads(T+2) issue in tile
// T+1 -> safe. WAR: stage(t+3)->buf(t-1); its readers (frags t-1, issued t-2)
// lgkm-completed before MFMA(t-1) < bar(t-1) < stage issue. 
#define CFENCE asm volatile("" ::: "memory")
DEVI void bar() { CFENCE; __builtin_amdgcn_s_barrier(); CFENCE; }
#define WAITVM(N) asm volatile("s_waitcnt vmcnt(" #N ")" ::: "memory")
#define PRIO1 __builtin_amdgcn_s_setprio(1)
#define PRIO0 __builtin_amdgcn_s_setprio(0)

#define MFMA32(A, B)                                                             \
    do {                                                                         \
        _Pragma("unroll") for (int mm = 0; mm < 8; ++mm)                         \
        _Pragma("unroll") for (int n = 0; n < 4; ++n)                            \
            acc[mm][n] = __builtin_amdgcn_mfma_i32_16x16x64_i8(                  \
                (A)[mm], (B)[n], acc[mm][n], 0, 0, 0);                           \
    } while (0)

#define LDFR(A, B, CB)                                                           \
    do {                                                                         \
        _Pragma("unroll") for (int mm = 0; mm < 8; ++mm)                         \
            (A)[mm] = smem4[(CB) + a_rd16 + mm * 64];                            \
        _Pragma("unroll") for (int n = 0; n < 4; ++n)                            \
            (B)[n] = smem4[(CB) + b_rd16 + n * 64];                              \
    } while (0)

__attribute__((amdgpu_waves_per_eu(2, 2)))
__global__ __launch_bounds__(512, 2)
void gemm15(const char* __restrict__ A8, const char* __restrict__ B8,
            const int* __restrict__ bias,
            const int* __restrict__ qm_p, const int* __restrict__ ex_p,
            const int* __restrict__ zp_p, int* __restrict__ out) {
    // LDS (16B units): 4 bufs x [A 256x4slots | B 256x4slots] = 4 x 32 KiB
    __shared__ i32x4 smem4[8192];
    char* smem = (char*)smem4;

    const int tid  = threadIdx.x;
    const int wid  = tid >> 6;
    const int lane = tid & 63;
    const int l15  = lane & 15;
    const int lks  = lane >> 4;
    const int wr   = wid >> 2;   // 0..1
    const int wc   = wid & 3;    // 0..3

    // XCD-bijective swizzle (256 % 8 == 0)
    const int bid = blockIdx.x;
    const int swz = (bid & 7) * 32 + (bid >> 3);
    const int bm  = swz >> 5;    // 0..7
    const int bn  = swz & 31;    // 0..31
    const int arow0 = bm * 256;
    const int brow0 = bn * 256;

    // T2 swizzle (r10-verified 0-conflict): phys slot = chunk ^ ((row>>1)&3)
    const int swsel = lks ^ ((l15 >> 1) & 3);
    const int a_rd16 = (wr * 128 + l15) * 4 + swsel;
    const int b_rd16 = 1024 + (wc * 64 + l15) * 4 + swsel;

    // staging: thread covers rows tid>>2 (+128), chunk st_c (inverse swizzle)
    const int st_c = (tid & 3) ^ ((tid >> 3) & 3);
    const char* agp = A8 + (size_t)(arow0 + (tid >> 2)) * Kdim + st_c * 16;
    const char* bgp = B8 + (size_t)(brow0 + (tid >> 2)) * Kdim + st_c * 16;

    auto stage = [&](int t, int cb) {   // cb in 16B units; 4 DMAs = 32 KB tile
        const int lb = cb * 16 + tid * 16;
        const size_t ko = (size_t)t * BK;
        gload_lds16(agp + ko,                      &smem[lb]);
        gload_lds16(agp + ko + (size_t)128 * Kdim, &smem[lb + 8192]);
        gload_lds16(bgp + ko,                      &smem[lb + 16384]);
        gload_lds16(bgp + ko + (size_t)128 * Kdim, &smem[lb + 24576]);
    };

    i32x4 acc[8][4] = {};
    i32x4 A0[8], B0[4], A1[8], B1[4];

    // prologue: 3 tiles staged; prove stage(0),stage(1); preload frags(0)
    stage(0, 0); stage(1, 2048); stage(2, 4096);
    WAITVM(4);
    bar();
    int c0 = 0, c1 = 2048, c2 = 4096, c3 = 6144;   // buf(t..t+3), 16B units
    LDFR(A0, B0, c0);

    for (int t = 0; t < NT; t += 2) {
        // ---- even: tile t (consumes A0/B0) ----
        if (t + 1 < NT) LDFR(A1, B1, c1);          // frags(t+1); no wait here
        if (t + 3 < NT) stage(t + 3, c3);
        PRIO1; MFMA32(A0, B0); PRIO0;
        if (t + 3 < NT) { WAITVM(4); } else { WAITVM(0); }
        bar();
        // ---- odd: tile t+1 (consumes A1/B1) ----
        if (t + 2 < NT) LDFR(A0, B0, c2);          // frags(t+2)
        if (t + 4 < NT) stage(t + 4, c0);
        PRIO1; MFMA32(A1, B1); PRIO0;
        if (t + 4 < NT) { WAITVM(4); } else { WAITVM(0); }
        bar();
        // rotate buffers by 2 tiles
        const int u0 = c0, u1 = c1;
        c0 = c2; c1 = c3; c2 = u0; c3 = u1;
    }

    // ---------------- epilogue: requantize ----------------
    const int qm = *qm_p;
    const int ex = *ex_p;
    const int zp = *zp_p;
    const int rm = (qm < 2147418112) ? ((qm + (1 << 15)) >> 16) : 32767;
    const int shifts = 15 - ex;
    const long long rnd = (shifts > 0) ? (1LL << (shifts - 1)) : 0;

    int bv[4];
#pragma unroll
    for (int n = 0; n < 4; ++n) bv[n] = bias[brow0 + wc * 64 + n * 16 + l15];

#pragma unroll
    for (int m = 0; m < 8; ++m) {
        const int row0 = arow0 + wr * 128 + m * 16 + lks * 4;
#pragma unroll
        for (int n = 0; n < 4; ++n) {
            const int col = brow0 + wc * 64 + n * 16 + l15;
#pragma unroll
            for (int j = 0; j < 4; ++j) {
                long long v = (long long)(acc[m][n][j] + bv[n]) * rm + rnd;
                v >>= shifts;
                v += zp;
                v = v < -128 ? -128 : (v > 127 ? 127 : v);
                out[(size_t)(row0 + j) * Ndim + col] = (int)v;
            }
        }
    }
}

extern "C" void kernel_launch(void* const* d_in, const int* in_sizes, int n_in,
                              void* d_out, int out_size, void* d_ws, size_t ws_size,
                              hipStream_t stream) {
    const int* x32  = (const int*)d_in[0];
    const int* w32  = (const int*)d_in[1];
    const int* bias = (const int*)d_in[2];
    const int* qm   = (const int*)d_in[3];
    const int* ex   = (const int*)d_in[4];
    const int* zp   = (const int*)d_in[5];
    int* out = (int*)d_out;

    char* xa = (char*)d_ws;
    char* wa = xa + (size_t)Bdim * Kdim;
    const int nx16 = Bdim * Kdim / 16;   // 524288
    const int nw16 = Ndim * Kdim / 16;   // 2097152
    pack_i32_to_i8<<<(nx16 + 255) / 256, 256, 0, stream>>>(x32, xa, nx16);
    pack_i32_to_i8<<<(nw16 + 255) / 256, 256, 0, stream>>>(w32, wa, nw16);

    const int grid = (Bdim / 256) * (Ndim / 256);   // 8 * 32 = 256
    gemm15<<<grid, 512, 0, stream>>>(xa, wa, bias, qm, ex, zp, out);
}